// Round 2
// baseline (380.690 us; speedup 1.0000x reference)
//
#include <hip/hip_runtime.h>

#define BATCH 8
#define SEQ   65536
#define CH    64
#define FILT  64
#define DLAT  256

// grid decomposition: 128 blocks per batch sample, 512 rows per block,
// 4 waves x 8 tiles x 16 rows. 1024 blocks total = 4 blocks/CU resident
// (VGPR<=128 -> 4 waves/SIMD) = 16 waves/CU for latency hiding.
#define BLK_PER_B  128
#define ROWS_PER_BLK (SEQ / BLK_PER_B)   // 512
#define TILES      8                      // per wave

typedef __bf16 bfrag  __attribute__((ext_vector_type(8)));
typedef float  floatx4 __attribute__((ext_vector_type(4)));

// ------------- prep: s, d, and folded kernel kmod[b][k][f][c] (bf16) -------
// kmod[b][k][f][c] = ker[k][c][f] * s[b][c] * d[b][f]
__global__ __launch_bounds__(256) void prep_kernel(
    const float* __restrict__ ltnt, const float* __restrict__ ker,
    const float* __restrict__ Wd,   const float* __restrict__ bd,
    __bf16* __restrict__ kmod)
{
    int b = blockIdx.x, tid = threadIdx.x;
    __shared__ float red[4][64];
    __shared__ float s_sh[64];
    __shared__ float d_sh[64];
    int f = tid & 63, p = tid >> 6;

    // s = softplus(ltnt @ Wd + bd) + 1
    float sum = 0.f;
    #pragma unroll 8
    for (int j = p * 64; j < p * 64 + 64; ++j)
        sum += ltnt[b * DLAT + j] * Wd[j * FILT + f];
    red[p][f] = sum;
    __syncthreads();
    if (tid < 64) {
        float tot = red[0][tid] + red[1][tid] + red[2][tid] + red[3][tid] + bd[tid];
        float sp = (tot > 20.f) ? tot : log1pf(expf(tot));
        s_sh[tid] = sp + 1.f;
    }
    __syncthreads();

    // d[f] = rsqrt( sum_{k,c} (ker[k,c,f]*s[c])^2 + eps )   (f32, matches ref)
    float s2 = 0.f;
    for (int k = 0; k < 3; ++k)
        #pragma unroll
        for (int c = p * 16; c < p * 16 + 16; ++c) {
            float w = ker[k * 4096 + c * 64 + f];
            float sc = s_sh[c];
            s2 += w * w * sc * sc;
        }
    __syncthreads();
    red[p][f] = s2;
    __syncthreads();
    if (tid < 64) {
        float tot = red[0][tid] + red[1][tid] + red[2][tid] + red[3][tid];
        d_sh[tid] = rsqrtf(tot + 1e-8f);
    }
    __syncthreads();

    // folded kernel, bf16, layout [k][f][c] contiguous in c
    for (int o = tid; o < 3 * 64 * 64; o += 256) {
        int k = o >> 12, ff = (o >> 6) & 63, c = o & 63;
        kmod[b * 12288 + o] = (__bf16)(ker[k * 4096 + c * 64 + ff] * s_sh[c] * d_sh[ff]);
    }
}

// ---------------------------- conv --------------------------------
struct RawA { float4 v[3][2][2]; };   // [tap k][chh][lo/hi float4]

__device__ __forceinline__ float4 scale4(float4 v, float s) {
    v.x *= s; v.y *= s; v.z *= s; v.w *= s; return v;
}

__device__ __forceinline__ RawA loadA(const float* __restrict__ xb,
                                      int r0, int m, int q) {
    RawA r;
    if (r0 >= 1 && r0 <= SEQ - 17) {            // interior fast path (uniform)
        const float* p = xb + (size_t)(r0 + m - 1) * CH + q * 8;
        #pragma unroll
        for (int k = 0; k < 3; ++k)
            #pragma unroll
            for (int h = 0; h < 2; ++h) {
                r.v[k][h][0] = *(const float4*)(p + k * CH + h * 32);
                r.v[k][h][1] = *(const float4*)(p + k * CH + h * 32 + 4);
            }
    } else {                                    // batch-edge tiles only
        #pragma unroll
        for (int k = 0; k < 3; ++k) {
            int g = r0 + m - 1 + k;
            bool ok = (unsigned)g < (unsigned)SEQ;
            const float* p = xb + (size_t)(ok ? g : 0) * CH + q * 8;
            float sc = ok ? 1.f : 0.f;
            #pragma unroll
            for (int h = 0; h < 2; ++h) {
                r.v[k][h][0] = scale4(*(const float4*)(p + h * 32), sc);
                r.v[k][h][1] = scale4(*(const float4*)(p + h * 32 + 4), sc);
            }
        }
    }
    return r;
}

__device__ __forceinline__ bfrag cvt8(float4 a, float4 b) {
    bfrag r;
    r[0] = (__bf16)a.x; r[1] = (__bf16)a.y; r[2] = (__bf16)a.z; r[3] = (__bf16)a.w;
    r[4] = (__bf16)b.x; r[5] = (__bf16)b.y; r[6] = (__bf16)b.z; r[7] = (__bf16)b.w;
    return r;
}

__global__ __launch_bounds__(256, 4) void conv_kernel(
    const float* __restrict__ data, const __bf16* __restrict__ kmod,
    float* __restrict__ out)
{
    // wave-private staging tile: 16 rows x 64 cols f32, XOR-swizzled.
    // swizzle: scol = col ^ ((((row&3) ^ (row>>2)) & 3) << 4)
    //  - acc writes (nt,r fixed; q varies): bank bit4 toggles with q -> 2-way max (free)
    //  - f4 reads  (i fixed; q,m vary):    uniform 8 slots/bank (b128 minimum)
    __shared__ float lds[4][16][64];   // 16 KiB / block

    int tid  = threadIdx.x;
    int b    = blockIdx.x >> 7;              // 128 blocks per batch
    int blk  = blockIdx.x & (BLK_PER_B - 1); // 512 rows per block
    int wave = tid >> 6, lane = tid & 63;
    int m = lane & 15, q = lane >> 4;

    // B fragments (folded kernel) -> registers, once. 24 frags = 96 VGPRs.
    const __bf16* kb = kmod + b * 12288;
    bfrag Bf[4][3][2];
    #pragma unroll
    for (int nt = 0; nt < 4; ++nt)
        #pragma unroll
        for (int k = 0; k < 3; ++k)
            #pragma unroll
            for (int h = 0; h < 2; ++h)
                Bf[nt][k][h] = *(const bfrag*)(kb + (k * 64 + nt * 16 + m) * 64 + h * 32 + q * 8);

    const float* xb = data + (size_t)b * SEQ * CH;
    float*       ob = out  + (size_t)b * SEQ * FILT;
    float*       lw = &lds[wave][0][0];

    // wave-interleaved 16-row tiles: r0 = blk*512 + wave*16 + t*64
    int base = blk * ROWS_PER_BLK + wave * 16;

    RawA raw = loadA(xb, base, m, q);
    bfrag Af[3][2];
    #pragma unroll
    for (int k = 0; k < 3; ++k)
        #pragma unroll
        for (int h = 0; h < 2; ++h)
            Af[k][h] = cvt8(raw.v[k][h][0], raw.v[k][h][1]);

    #pragma unroll 1
    for (int t = 0; t < TILES; ++t) {
        int r0 = base + t * 64;

        if (t < TILES - 1)              // issue next tile's loads (prefetch)
            raw = loadA(xb, r0 + 64, m, q);

        floatx4 acc[4] = {floatx4{0,0,0,0}, floatx4{0,0,0,0},
                          floatx4{0,0,0,0}, floatx4{0,0,0,0}};
        #pragma unroll
        for (int nt = 0; nt < 4; ++nt)
            #pragma unroll
            for (int k = 0; k < 3; ++k)
                #pragma unroll
                for (int h = 0; h < 2; ++h)
                    acc[nt] = __builtin_amdgcn_mfma_f32_16x16x32_bf16(
                        Af[k][h], Bf[nt][k][h], acc[nt], 0, 0, 0);

        // --- stage accumulator tile through wave-private LDS (swizzled) ---
        // acc[nt][r] = out[row = q*4+r][col = nt*16+m]
        #pragma unroll
        for (int nt = 0; nt < 4; ++nt)
            #pragma unroll
            for (int r = 0; r < 4; ++r) {
                int row = q * 4 + r;                       // row&3 == r, row>>2 == q
                int sc  = (nt * 16 + m) ^ ((((r ^ q) & 3)) << 4);
                lw[row * 64 + sc] = acc[nt][r];
            }

        // --- read back contiguous float4 and store fully coalesced ---
        // instruction i: rows i*4+q, cols 4m..4m+3 -> wave writes 1 KiB contiguous
        float* op = ob + (size_t)r0 * FILT;
        #pragma unroll
        for (int i = 0; i < 4; ++i) {
            int row = i * 4 + q;                           // row&3 == q, row>>2 == i
            int sc  = (m * 4) ^ ((((q ^ i) & 3)) << 4);
            floatx4 v = *(const floatx4*)(lw + row * 64 + sc);
            __builtin_nontemporal_store(v,
                (floatx4*)(op + (size_t)row * FILT + m * 4));
        }

        if (t < TILES - 1) {            // convert prefetched tile (waits here,
            #pragma unroll              //  after MFMAs+stores, not before)
            for (int k = 0; k < 3; ++k)
                #pragma unroll
                for (int h = 0; h < 2; ++h)
                    Af[k][h] = cvt8(raw.v[k][h][0], raw.v[k][h][1]);
        }
    }
}

// ---------------------------------------------------------------------------
extern "C" void kernel_launch(void* const* d_in, const int* in_sizes, int n_in,
                              void* d_out, int out_size, void* d_ws, size_t ws_size,
                              hipStream_t stream) {
    const float* data = (const float*)d_in[0];
    const float* ltnt = (const float*)d_in[1];
    const float* ker  = (const float*)d_in[2];
    const float* Wd   = (const float*)d_in[3];
    const float* bd   = (const float*)d_in[4];
    float* out = (float*)d_out;

    __bf16* kmod = (__bf16*)d_ws;     // 8 * 12288 bf16 = 192 KiB

    prep_kernel<<<BATCH, 256, 0, stream>>>(ltnt, ker, Wd, bd, kmod);
    conv_kernel<<<BATCH * BLK_PER_B, 256, 0, stream>>>(data, kmod, out);
}

// Round 3
// 268.974 us; speedup vs baseline: 1.4153x; 1.4153x over previous
//
#include <hip/hip_runtime.h>

#define BATCH 8
#define SEQ   65536
#define CH    64
#define FILT  64
#define DLAT  256

// grid decomposition: 128 blocks per batch sample, 512 rows per block,
// 4 waves x 8 tiles x 16 rows. 1024 blocks total -> 4 blocks/CU resident
// (VGPR ~108 rounds to 112; 512/112 = 4 waves/SIMD). Do NOT clamp
// registers via launch_bounds min-waves: (256,4) forced VGPR=64 and
// spilled Bf/raw to scratch (FETCH 66->430 MB, R2 regression).
#define BLK_PER_B  128
#define ROWS_PER_BLK (SEQ / BLK_PER_B)   // 512
#define TILES      8                      // per wave

typedef __bf16 bfrag  __attribute__((ext_vector_type(8)));
typedef float  floatx4 __attribute__((ext_vector_type(4)));

// ------------- prep: s, d, and folded kernel kmod[b][k][f][c] (bf16) -------
// kmod[b][k][f][c] = ker[k][c][f] * s[b][c] * d[b][f]
__global__ __launch_bounds__(256) void prep_kernel(
    const float* __restrict__ ltnt, const float* __restrict__ ker,
    const float* __restrict__ Wd,   const float* __restrict__ bd,
    __bf16* __restrict__ kmod)
{
    int b = blockIdx.x, tid = threadIdx.x;
    __shared__ float red[4][64];
    __shared__ float s_sh[64];
    __shared__ float d_sh[64];
    int f = tid & 63, p = tid >> 6;

    // s = softplus(ltnt @ Wd + bd) + 1
    float sum = 0.f;
    #pragma unroll 8
    for (int j = p * 64; j < p * 64 + 64; ++j)
        sum += ltnt[b * DLAT + j] * Wd[j * FILT + f];
    red[p][f] = sum;
    __syncthreads();
    if (tid < 64) {
        float tot = red[0][tid] + red[1][tid] + red[2][tid] + red[3][tid] + bd[tid];
        float sp = (tot > 20.f) ? tot : log1pf(expf(tot));
        s_sh[tid] = sp + 1.f;
    }
    __syncthreads();

    // d[f] = rsqrt( sum_{k,c} (ker[k,c,f]*s[c])^2 + eps )   (f32, matches ref)
    float s2 = 0.f;
    for (int k = 0; k < 3; ++k)
        #pragma unroll
        for (int c = p * 16; c < p * 16 + 16; ++c) {
            float w = ker[k * 4096 + c * 64 + f];
            float sc = s_sh[c];
            s2 += w * w * sc * sc;
        }
    __syncthreads();
    red[p][f] = s2;
    __syncthreads();
    if (tid < 64) {
        float tot = red[0][tid] + red[1][tid] + red[2][tid] + red[3][tid];
        d_sh[tid] = rsqrtf(tot + 1e-8f);
    }
    __syncthreads();

    // folded kernel, bf16, layout [k][f][c] contiguous in c
    for (int o = tid; o < 3 * 64 * 64; o += 256) {
        int k = o >> 12, ff = (o >> 6) & 63, c = o & 63;
        kmod[b * 12288 + o] = (__bf16)(ker[k * 4096 + c * 64 + ff] * s_sh[c] * d_sh[ff]);
    }
}

// ---------------------------- conv --------------------------------
struct RawA { float4 v[3][2][2]; };   // [tap k][chh][lo/hi float4]

__device__ __forceinline__ float4 scale4(float4 v, float s) {
    v.x *= s; v.y *= s; v.z *= s; v.w *= s; return v;
}

__device__ __forceinline__ RawA loadA(const float* __restrict__ xb,
                                      int r0, int m, int q) {
    RawA r;
    if (r0 >= 1 && r0 <= SEQ - 17) {            // interior fast path (uniform)
        const float* p = xb + (size_t)(r0 + m - 1) * CH + q * 8;
        #pragma unroll
        for (int k = 0; k < 3; ++k)
            #pragma unroll
            for (int h = 0; h < 2; ++h) {
                r.v[k][h][0] = *(const float4*)(p + k * CH + h * 32);
                r.v[k][h][1] = *(const float4*)(p + k * CH + h * 32 + 4);
            }
    } else {                                    // batch-edge tiles only
        #pragma unroll
        for (int k = 0; k < 3; ++k) {
            int g = r0 + m - 1 + k;
            bool ok = (unsigned)g < (unsigned)SEQ;
            const float* p = xb + (size_t)(ok ? g : 0) * CH + q * 8;
            float sc = ok ? 1.f : 0.f;
            #pragma unroll
            for (int h = 0; h < 2; ++h) {
                r.v[k][h][0] = scale4(*(const float4*)(p + h * 32), sc);
                r.v[k][h][1] = scale4(*(const float4*)(p + h * 32 + 4), sc);
            }
        }
    }
    return r;
}

__device__ __forceinline__ bfrag cvt8(float4 a, float4 b) {
    bfrag r;
    r[0] = (__bf16)a.x; r[1] = (__bf16)a.y; r[2] = (__bf16)a.z; r[3] = (__bf16)a.w;
    r[4] = (__bf16)b.x; r[5] = (__bf16)b.y; r[6] = (__bf16)b.z; r[7] = (__bf16)b.w;
    return r;
}

__global__ __launch_bounds__(256, 2) void conv_kernel(
    const float* __restrict__ data, const __bf16* __restrict__ kmod,
    float* __restrict__ out)
{
    // wave-private staging tile: 16 rows x 64 cols f32, XOR-swizzled.
    // swizzle: scol = col ^ ((((row&3) ^ (row>>2)) & 3) << 4)
    //  - acc writes (nt,r fixed; q varies): bank bit4 toggles with q -> 2-way max (free)
    //  - f4 reads  (i fixed; q,m vary):    uniform 8 slots/bank (b128 minimum)
    __shared__ float lds[4][16][64];   // 16 KiB / block

    int tid  = threadIdx.x;
    int b    = blockIdx.x >> 7;              // 128 blocks per batch
    int blk  = blockIdx.x & (BLK_PER_B - 1); // 512 rows per block
    int wave = tid >> 6, lane = tid & 63;
    int m = lane & 15, q = lane >> 4;

    // B fragments (folded kernel) -> registers, once. 24 frags = 96 VGPRs.
    const __bf16* kb = kmod + b * 12288;
    bfrag Bf[4][3][2];
    #pragma unroll
    for (int nt = 0; nt < 4; ++nt)
        #pragma unroll
        for (int k = 0; k < 3; ++k)
            #pragma unroll
            for (int h = 0; h < 2; ++h)
                Bf[nt][k][h] = *(const bfrag*)(kb + (k * 64 + nt * 16 + m) * 64 + h * 32 + q * 8);

    const float* xb = data + (size_t)b * SEQ * CH;
    float*       ob = out  + (size_t)b * SEQ * FILT;
    float*       lw = &lds[wave][0][0];

    // wave-interleaved 16-row tiles: r0 = blk*512 + wave*16 + t*64
    int base = blk * ROWS_PER_BLK + wave * 16;

    RawA raw = loadA(xb, base, m, q);
    bfrag Af[3][2];
    #pragma unroll
    for (int k = 0; k < 3; ++k)
        #pragma unroll
        for (int h = 0; h < 2; ++h)
            Af[k][h] = cvt8(raw.v[k][h][0], raw.v[k][h][1]);

    #pragma unroll 1
    for (int t = 0; t < TILES; ++t) {
        int r0 = base + t * 64;

        if (t < TILES - 1)              // issue next tile's loads (prefetch)
            raw = loadA(xb, r0 + 64, m, q);

        floatx4 acc[4] = {floatx4{0,0,0,0}, floatx4{0,0,0,0},
                          floatx4{0,0,0,0}, floatx4{0,0,0,0}};
        #pragma unroll
        for (int nt = 0; nt < 4; ++nt)
            #pragma unroll
            for (int k = 0; k < 3; ++k)
                #pragma unroll
                for (int h = 0; h < 2; ++h)
                    acc[nt] = __builtin_amdgcn_mfma_f32_16x16x32_bf16(
                        Af[k][h], Bf[nt][k][h], acc[nt], 0, 0, 0);

        // --- stage accumulator tile through wave-private LDS (swizzled) ---
        // acc[nt][r] = out[row = q*4+r][col = nt*16+m]
        #pragma unroll
        for (int nt = 0; nt < 4; ++nt)
            #pragma unroll
            for (int r = 0; r < 4; ++r) {
                int row = q * 4 + r;                       // row&3 == r, row>>2 == q
                int sc  = (nt * 16 + m) ^ ((((r ^ q) & 3)) << 4);
                lw[row * 64 + sc] = acc[nt][r];
            }

        // --- read back contiguous float4 and store fully coalesced ---
        // instruction i: rows i*4+q, cols 4m..4m+3 -> wave writes 1 KiB contiguous
        float* op = ob + (size_t)r0 * FILT;
        #pragma unroll
        for (int i = 0; i < 4; ++i) {
            int row = i * 4 + q;                           // row&3 == q, row>>2 == i
            int sc  = (m * 4) ^ ((((q ^ i) & 3)) << 4);
            floatx4 v = *(const floatx4*)(lw + row * 64 + sc);
            __builtin_nontemporal_store(v,
                (floatx4*)(op + (size_t)row * FILT + m * 4));
        }

        if (t < TILES - 1) {            // convert prefetched tile (waits here,
            #pragma unroll              //  after MFMAs+stores, not before)
            for (int k = 0; k < 3; ++k)
                #pragma unroll
                for (int h = 0; h < 2; ++h)
                    Af[k][h] = cvt8(raw.v[k][h][0], raw.v[k][h][1]);
        }
    }
}

// ---------------------------------------------------------------------------
extern "C" void kernel_launch(void* const* d_in, const int* in_sizes, int n_in,
                              void* d_out, int out_size, void* d_ws, size_t ws_size,
                              hipStream_t stream) {
    const float* data = (const float*)d_in[0];
    const float* ltnt = (const float*)d_in[1];
    const float* ker  = (const float*)d_in[2];
    const float* Wd   = (const float*)d_in[3];
    const float* bd   = (const float*)d_in[4];
    float* out = (float*)d_out;

    __bf16* kmod = (__bf16*)d_ws;     // 8 * 12288 bf16 = 192 KiB

    prep_kernel<<<BATCH, 256, 0, stream>>>(ltnt, ker, Wd, bd, kmod);
    conv_kernel<<<BATCH * BLK_PER_B, 256, 0, stream>>>(data, kmod, out);
}

// Round 4
// 264.743 us; speedup vs baseline: 1.4380x; 1.0160x over previous
//
#include <hip/hip_runtime.h>

#define BATCH 8
#define SEQ   65536
#define CH    64
#define FILT  64
#define DLAT  256

// 128 blocks/batch, 512 rows/block, 8 block-tiles of 64 rows.
// Wave w computes filter stripe [w*16, w*16+16) for all 64 rows of the tile.
// A (x rows, bf16) is block-shared in LDS; B (folded kernel) is 24 regs/wave.
// Register design target: <=128 unified regs -> 4 waves/SIMD resident.
#define BLK_PER_B   128
#define ROWS_PER_BLK 512
#define TILE_ROWS    64
#define TILES        (ROWS_PER_BLK / TILE_ROWS)   // 8
#define AROWS        66                            // 64 + 2 halo rows
#define ACHUNKS      (AROWS * 8)                   // 528 x 16B chunks

typedef __bf16 bfrag  __attribute__((ext_vector_type(8)));
typedef float  floatx4 __attribute__((ext_vector_type(4)));

// ------------- prep: s, d, and folded kernel kmod[b][k][f][c] (bf16) -------
// kmod[b][k][f][c] = ker[k][c][f] * s[b][c] * d[b][f]
__global__ __launch_bounds__(256) void prep_kernel(
    const float* __restrict__ ltnt, const float* __restrict__ ker,
    const float* __restrict__ Wd,   const float* __restrict__ bd,
    __bf16* __restrict__ kmod)
{
    int b = blockIdx.x, tid = threadIdx.x;
    __shared__ float red[4][64];
    __shared__ float s_sh[64];
    __shared__ float d_sh[64];
    int f = tid & 63, p = tid >> 6;

    // s = softplus(ltnt @ Wd + bd) + 1
    float sum = 0.f;
    #pragma unroll 8
    for (int j = p * 64; j < p * 64 + 64; ++j)
        sum += ltnt[b * DLAT + j] * Wd[j * FILT + f];
    red[p][f] = sum;
    __syncthreads();
    if (tid < 64) {
        float tot = red[0][tid] + red[1][tid] + red[2][tid] + red[3][tid] + bd[tid];
        float sp = (tot > 20.f) ? tot : log1pf(expf(tot));
        s_sh[tid] = sp + 1.f;
    }
    __syncthreads();

    // d[f] = rsqrt( sum_{k,c} (ker[k,c,f]*s[c])^2 + eps )   (f32, matches ref)
    float s2 = 0.f;
    for (int k = 0; k < 3; ++k)
        #pragma unroll
        for (int c = p * 16; c < p * 16 + 16; ++c) {
            float w = ker[k * 4096 + c * 64 + f];
            float sc = s_sh[c];
            s2 += w * w * sc * sc;
        }
    __syncthreads();
    red[p][f] = s2;
    __syncthreads();
    if (tid < 64) {
        float tot = red[0][tid] + red[1][tid] + red[2][tid] + red[3][tid];
        d_sh[tid] = rsqrtf(tot + 1e-8f);
    }
    __syncthreads();

    // folded kernel, bf16, layout [k][f][c] contiguous in c
    for (int o = tid; o < 3 * 64 * 64; o += 256) {
        int k = o >> 12, ff = (o >> 6) & 63, c = o & 63;
        kmod[b * 12288 + o] = (__bf16)(ker[k * 4096 + c * 64 + ff] * s_sh[c] * d_sh[ff]);
    }
}

// ---------------------------- conv --------------------------------
__device__ __forceinline__ float4 scale4(float4 v, float s) {
    v.x *= s; v.y *= s; v.z *= s; v.w *= s; return v;
}

__device__ __forceinline__ bfrag cvt8(float4 a, float4 b) {
    bfrag r;
    r[0] = (__bf16)a.x; r[1] = (__bf16)a.y; r[2] = (__bf16)a.z; r[3] = (__bf16)a.w;
    r[4] = (__bf16)b.x; r[5] = (__bf16)b.y; r[6] = (__bf16)b.z; r[7] = (__bf16)b.w;
    return r;
}

// issue global loads for one A tile (rows r0-1 .. r0+64) into registers.
// chunk id = i*256+tid: rho = id>>3 (LDS row), c = id&7 (8-channel group).
// OOB (halo beyond batch edge, or id>=ACHUNKS) -> load row 0, scale 0.
__device__ __forceinline__ void stage_load(float4 pre[3][2],
                                           const float* __restrict__ xb,
                                           int r0, int tid) {
    #pragma unroll
    for (int i = 0; i < 3; ++i) {
        int id  = i * 256 + tid;
        int rho = id >> 3, c = id & 7;
        int g   = r0 - 1 + rho;
        bool ok = (id < ACHUNKS) && ((unsigned)g < (unsigned)SEQ);
        const float* p = xb + (size_t)(ok ? g : 0) * CH + c * 8;
        float s = ok ? 1.f : 0.f;
        pre[i][0] = scale4(*(const float4*)p, s);
        pre[i][1] = scale4(*(const float4*)(p + 4), s);
    }
}

// convert staged registers to bf16 and write to swizzled LDS A tile.
// element index = (rho*64 + c*8) ^ ((rho&7)<<3)  -- 16B-chunk XOR swizzle so
// ds_read_b128 at row-stride 128B spreads across bank groups (2-way max).
__device__ __forceinline__ void stage_write(__bf16* __restrict__ A,
                                            float4 pre[3][2], int tid) {
    #pragma unroll
    for (int i = 0; i < 3; ++i) {
        int id = i * 256 + tid;
        if (id < ACHUNKS) {
            int rho = id >> 3, c = id & 7;
            int idx = (rho * 64 + c * 8) ^ ((rho & 7) << 3);
            *(bfrag*)(A + idx) = cvt8(pre[i][0], pre[i][1]);
        }
    }
}

__global__ __launch_bounds__(256, 4) void conv_kernel(
    const float* __restrict__ data, const __bf16* __restrict__ kmod,
    float* __restrict__ out)
{
    __shared__ __bf16 Abuf[2][AROWS * 64];   // 2 x 8448 B, XOR-swizzled bf16
    __shared__ float  OutT[64 * 64];         // 16 KiB output transpose tile

    int tid  = threadIdx.x;
    int b    = blockIdx.x >> 7;              // 128 blocks per batch
    int blk  = blockIdx.x & (BLK_PER_B - 1);
    int wave = tid >> 6, lane = tid & 63;
    int m = lane & 15, q = lane >> 4;

    // B fragments for this wave's filter stripe (nt == wave): 6 frags = 24 regs
    const __bf16* kb = kmod + b * 12288;
    bfrag Bf[3][2];
    #pragma unroll
    for (int k = 0; k < 3; ++k)
        #pragma unroll
        for (int h = 0; h < 2; ++h)
            Bf[k][h] = *(const bfrag*)(kb + (k * 64 + wave * 16 + m) * 64 + h * 32 + q * 8);

    const float* xb = data + (size_t)b * SEQ * CH;
    float*       ob = out  + (size_t)b * SEQ * FILT;
    int base = blk * ROWS_PER_BLK;

    float4 pre[3][2];                        // 24 regs staged prefetch
    stage_load(pre, xb, base, tid);

    #pragma unroll 1
    for (int t = 0; t < TILES; ++t) {
        int r0 = base + t * TILE_ROWS;
        __bf16* A = Abuf[t & 1];

        stage_write(A, pre, tid);
        __syncthreads();                      // S1: A tile ready; OutT(t-1) reads done

        if (t + 1 < TILES)                    // issue next tile's loads early;
            stage_load(pre, xb, r0 + TILE_ROWS, tid);   // latency hides under compute

        // ---- compute: 4 row-tiles x (3 taps x 2 ch-halves) MFMA ----
        floatx4 acc[4];
        #pragma unroll
        for (int rt = 0; rt < 4; ++rt) acc[rt] = floatx4{0, 0, 0, 0};

        #pragma unroll
        for (int rt = 0; rt < 4; ++rt) {
            #pragma unroll
            for (int k = 0; k < 3; ++k)
                #pragma unroll
                for (int h = 0; h < 2; ++h) {
                    int rho = rt * 16 + m + k;               // LDS row (r0-1 .. r0+64)
                    bfrag a = *(const bfrag*)(A +
                        ((rho * 64 + h * 32 + q * 8) ^ ((rho & 7) << 3)));
                    acc[rt] = __builtin_amdgcn_mfma_f32_16x16x32_bf16(
                        a, Bf[k][h], acc[rt], 0, 0, 0);
                }
        }

        // ---- acc -> OutT (swizzled: col ^ (q<<4) breaks q-lane 4-way) ----
        // acc[rt][r] = out[row = rt*16 + q*4 + r][col = wave*16 + m]
        #pragma unroll
        for (int rt = 0; rt < 4; ++rt)
            #pragma unroll
            for (int r = 0; r < 4; ++r) {
                int row = rt * 16 + q * 4 + r;
                int col = (wave * 16 + m) ^ (q << 4);
                OutT[row * 64 + col] = acc[rt][r];
            }
        __syncthreads();                      // S2: OutT complete

        // ---- read full rows and store coalesced NT dwordx4 ----
        // id = it*256+tid: row = id>>4, c = id&15; stored col x lives at
        // x ^ ((row>>2 & 3)<<4); (row>>2) is uniform per instruction.
        #pragma unroll
        for (int it = 0; it < 4; ++it) {
            int id  = it * 256 + tid;
            int row = id >> 4, c = id & 15;
            int scol = (c * 4) ^ (((row >> 2) & 3) << 4);
            floatx4 v = *(const floatx4*)(OutT + row * 64 + scol);
            __builtin_nontemporal_store(v,
                (floatx4*)(ob + (size_t)(r0 + row) * FILT + c * 4));
        }
        // next iter's stage_write(Abuf[(t+1)&1]) is safe: reads of that buffer
        // finished before S2(t-1); OutT(t+1) writes are after S1(t+1), which
        // all waves reach only after finishing OutT(t) reads above.
    }
}

// ---------------------------------------------------------------------------
extern "C" void kernel_launch(void* const* d_in, const int* in_sizes, int n_in,
                              void* d_out, int out_size, void* d_ws, size_t ws_size,
                              hipStream_t stream) {
    const float* data = (const float*)d_in[0];
    const float* ltnt = (const float*)d_in[1];
    const float* ker  = (const float*)d_in[2];
    const float* Wd   = (const float*)d_in[3];
    const float* bd   = (const float*)d_in[4];
    float* out = (float*)d_out;

    __bf16* kmod = (__bf16*)d_ws;     // 8 * 12288 bf16 = 192 KiB

    prep_kernel<<<BATCH, 256, 0, stream>>>(ltnt, ker, Wd, bd, kmod);
    conv_kernel<<<BATCH * BLK_PER_B, 256, 0, stream>>>(data, kmod, out);
}

// Round 5
// 264.000 us; speedup vs baseline: 1.4420x; 1.0028x over previous
//
#include <hip/hip_runtime.h>

#define BATCH 8
#define SEQ   65536
#define CH    64
#define FILT  64
#define DLAT  256

// 128 blocks/batch, 512 rows/block, 8 block-tiles of 64 rows.
// Wave w computes filter stripe [w*16, w*16+16) for all 64 rows of the tile.
// A (x rows, bf16) is block-shared in LDS; B (folded kernel) is 24 regs/wave.
// R5 experiment: PLAIN stores (not nontemporal). R0-R4 all converged to
// dur ~= WRITE_SIZE / 1.5 TB/s regardless of structure/occupancy -> NT
// stores ack from HBM inside the per-tile vmcnt(0)+barrier drain. Plain
// stores ack from L2; writeback decouples from the wave's critical path.
#define BLK_PER_B   128
#define ROWS_PER_BLK 512
#define TILE_ROWS    64
#define TILES        (ROWS_PER_BLK / TILE_ROWS)   // 8
#define AROWS        66                            // 64 + 2 halo rows
#define ACHUNKS      (AROWS * 8)                   // 528 x 16B chunks

typedef __bf16 bfrag  __attribute__((ext_vector_type(8)));
typedef float  floatx4 __attribute__((ext_vector_type(4)));

// ------------- prep: s, d, and folded kernel kmod[b][k][f][c] (bf16) -------
// kmod[b][k][f][c] = ker[k][c][f] * s[b][c] * d[b][f]
__global__ __launch_bounds__(256) void prep_kernel(
    const float* __restrict__ ltnt, const float* __restrict__ ker,
    const float* __restrict__ Wd,   const float* __restrict__ bd,
    __bf16* __restrict__ kmod)
{
    int b = blockIdx.x, tid = threadIdx.x;
    __shared__ float red[4][64];
    __shared__ float s_sh[64];
    __shared__ float d_sh[64];
    int f = tid & 63, p = tid >> 6;

    // s = softplus(ltnt @ Wd + bd) + 1
    float sum = 0.f;
    #pragma unroll 8
    for (int j = p * 64; j < p * 64 + 64; ++j)
        sum += ltnt[b * DLAT + j] * Wd[j * FILT + f];
    red[p][f] = sum;
    __syncthreads();
    if (tid < 64) {
        float tot = red[0][tid] + red[1][tid] + red[2][tid] + red[3][tid] + bd[tid];
        float sp = (tot > 20.f) ? tot : log1pf(expf(tot));
        s_sh[tid] = sp + 1.f;
    }
    __syncthreads();

    // d[f] = rsqrt( sum_{k,c} (ker[k,c,f]*s[c])^2 + eps )   (f32, matches ref)
    float s2 = 0.f;
    for (int k = 0; k < 3; ++k)
        #pragma unroll
        for (int c = p * 16; c < p * 16 + 16; ++c) {
            float w = ker[k * 4096 + c * 64 + f];
            float sc = s_sh[c];
            s2 += w * w * sc * sc;
        }
    __syncthreads();
    red[p][f] = s2;
    __syncthreads();
    if (tid < 64) {
        float tot = red[0][tid] + red[1][tid] + red[2][tid] + red[3][tid];
        d_sh[tid] = rsqrtf(tot + 1e-8f);
    }
    __syncthreads();

    // folded kernel, bf16, layout [k][f][c] contiguous in c
    for (int o = tid; o < 3 * 64 * 64; o += 256) {
        int k = o >> 12, ff = (o >> 6) & 63, c = o & 63;
        kmod[b * 12288 + o] = (__bf16)(ker[k * 4096 + c * 64 + ff] * s_sh[c] * d_sh[ff]);
    }
}

// ---------------------------- conv --------------------------------
__device__ __forceinline__ float4 scale4(float4 v, float s) {
    v.x *= s; v.y *= s; v.z *= s; v.w *= s; return v;
}

__device__ __forceinline__ bfrag cvt8(float4 a, float4 b) {
    bfrag r;
    r[0] = (__bf16)a.x; r[1] = (__bf16)a.y; r[2] = (__bf16)a.z; r[3] = (__bf16)a.w;
    r[4] = (__bf16)b.x; r[5] = (__bf16)b.y; r[6] = (__bf16)b.z; r[7] = (__bf16)b.w;
    return r;
}

// issue global loads for one A tile (rows r0-1 .. r0+64) into registers.
// chunk id = i*256+tid: rho = id>>3 (LDS row), c = id&7 (8-channel group).
// OOB (halo beyond batch edge, or id>=ACHUNKS) -> load row 0, scale 0.
__device__ __forceinline__ void stage_load(float4 pre[3][2],
                                           const float* __restrict__ xb,
                                           int r0, int tid) {
    #pragma unroll
    for (int i = 0; i < 3; ++i) {
        int id  = i * 256 + tid;
        int rho = id >> 3, c = id & 7;
        int g   = r0 - 1 + rho;
        bool ok = (id < ACHUNKS) && ((unsigned)g < (unsigned)SEQ);
        const float* p = xb + (size_t)(ok ? g : 0) * CH + c * 8;
        float s = ok ? 1.f : 0.f;
        pre[i][0] = scale4(*(const float4*)p, s);
        pre[i][1] = scale4(*(const float4*)(p + 4), s);
    }
}

// convert staged registers to bf16 and write to swizzled LDS A tile.
// element index = (rho*64 + c*8) ^ ((rho&7)<<3)  -- 16B-chunk XOR swizzle so
// ds_read_b128 at row-stride 128B spreads across bank groups (2-way max).
__device__ __forceinline__ void stage_write(__bf16* __restrict__ A,
                                            float4 pre[3][2], int tid) {
    #pragma unroll
    for (int i = 0; i < 3; ++i) {
        int id = i * 256 + tid;
        if (id < ACHUNKS) {
            int rho = id >> 3, c = id & 7;
            int idx = (rho * 64 + c * 8) ^ ((rho & 7) << 3);
            *(bfrag*)(A + idx) = cvt8(pre[i][0], pre[i][1]);
        }
    }
}

__global__ __launch_bounds__(256, 4) void conv_kernel(
    const float* __restrict__ data, const __bf16* __restrict__ kmod,
    float* __restrict__ out)
{
    __shared__ __bf16 Abuf[2][AROWS * 64];   // 2 x 8448 B, XOR-swizzled bf16
    __shared__ float  OutT[64 * 64];         // 16 KiB output transpose tile

    int tid  = threadIdx.x;
    int b    = blockIdx.x >> 7;              // 128 blocks per batch
    int blk  = blockIdx.x & (BLK_PER_B - 1);
    int wave = tid >> 6, lane = tid & 63;
    int m = lane & 15, q = lane >> 4;

    // B fragments for this wave's filter stripe (nt == wave): 6 frags = 24 regs
    const __bf16* kb = kmod + b * 12288;
    bfrag Bf[3][2];
    #pragma unroll
    for (int k = 0; k < 3; ++k)
        #pragma unroll
        for (int h = 0; h < 2; ++h)
            Bf[k][h] = *(const bfrag*)(kb + (k * 64 + wave * 16 + m) * 64 + h * 32 + q * 8);

    const float* xb = data + (size_t)b * SEQ * CH;
    float*       ob = out  + (size_t)b * SEQ * FILT;
    int base = blk * ROWS_PER_BLK;

    float4 pre[3][2];                        // 24 regs staged prefetch
    stage_load(pre, xb, base, tid);

    #pragma unroll 1
    for (int t = 0; t < TILES; ++t) {
        int r0 = base + t * TILE_ROWS;
        __bf16* A = Abuf[t & 1];

        stage_write(A, pre, tid);
        __syncthreads();                      // S1: A tile ready; OutT(t-1) reads done

        if (t + 1 < TILES)                    // issue next tile's loads early;
            stage_load(pre, xb, r0 + TILE_ROWS, tid);   // latency hides under compute

        // ---- compute: 4 row-tiles x (3 taps x 2 ch-halves) MFMA ----
        floatx4 acc[4];
        #pragma unroll
        for (int rt = 0; rt < 4; ++rt) acc[rt] = floatx4{0, 0, 0, 0};

        #pragma unroll
        for (int rt = 0; rt < 4; ++rt) {
            #pragma unroll
            for (int k = 0; k < 3; ++k)
                #pragma unroll
                for (int h = 0; h < 2; ++h) {
                    int rho = rt * 16 + m + k;               // LDS row (r0-1 .. r0+64)
                    bfrag a = *(const bfrag*)(A +
                        ((rho * 64 + h * 32 + q * 8) ^ ((rho & 7) << 3)));
                    acc[rt] = __builtin_amdgcn_mfma_f32_16x16x32_bf16(
                        a, Bf[k][h], acc[rt], 0, 0, 0);
                }
        }

        // ---- acc -> OutT (swizzled: col ^ (q<<4) breaks q-lane 4-way) ----
        // acc[rt][r] = out[row = rt*16 + q*4 + r][col = wave*16 + m]
        #pragma unroll
        for (int rt = 0; rt < 4; ++rt)
            #pragma unroll
            for (int r = 0; r < 4; ++r) {
                int row = rt * 16 + q * 4 + r;
                int col = (wave * 16 + m) ^ (q << 4);
                OutT[row * 64 + col] = acc[rt][r];
            }
        __syncthreads();                      // S2: OutT complete

        // ---- read full rows and store coalesced dwordx4 (PLAIN, ack from L2) ----
        // id = it*256+tid: row = id>>4, c = id&15; stored col x lives at
        // x ^ ((row>>2 & 3)<<4); (row>>2) is uniform per instruction.
        #pragma unroll
        for (int it = 0; it < 4; ++it) {
            int id  = it * 256 + tid;
            int row = id >> 4, c = id & 15;
            int scol = (c * 4) ^ (((row >> 2) & 3) << 4);
            floatx4 v = *(const floatx4*)(OutT + row * 64 + scol);
            *(floatx4*)(ob + (size_t)(r0 + row) * FILT + c * 4) = v;
        }
        // next iter's stage_write(Abuf[(t+1)&1]) is safe: reads of that buffer
        // finished before S2(t-1); OutT(t+1) writes are after S1(t+1), which
        // all waves reach only after finishing OutT(t) reads above.
    }
}

// ---------------------------------------------------------------------------
extern "C" void kernel_launch(void* const* d_in, const int* in_sizes, int n_in,
                              void* d_out, int out_size, void* d_ws, size_t ws_size,
                              hipStream_t stream) {
    const float* data = (const float*)d_in[0];
    const float* ltnt = (const float*)d_in[1];
    const float* ker  = (const float*)d_in[2];
    const float* Wd   = (const float*)d_in[3];
    const float* bd   = (const float*)d_in[4];
    float* out = (float*)d_out;

    __bf16* kmod = (__bf16*)d_ws;     // 8 * 12288 bf16 = 192 KiB

    prep_kernel<<<BATCH, 256, 0, stream>>>(ltnt, ker, Wd, bd, kmod);
    conv_kernel<<<BATCH * BLK_PER_B, 256, 0, stream>>>(data, kmod, out);
}

// Round 6
// 263.609 us; speedup vs baseline: 1.4442x; 1.0015x over previous
//
#include <hip/hip_runtime.h>

#define BATCH 8
#define SEQ   65536
#define CH    64
#define FILT  64
#define DLAT  256

// 128 blocks/batch, 512 rows/block, 8 block-tiles of 64 rows.
// Wave w computes filter stripe [w*16, w*16+16) for all 64 rows of the tile.
// R6 experiment: LDS-only barriers. __syncthreads() compiles to
// "s_waitcnt vmcnt(0) lgkmcnt(0); s_barrier", which force-drains ALL
// outstanding global stores twice per tile -> store commit happens in
// synchronized bursts inside a wait (R0-R5 invariant: dur ~= WRITE/1.5TB/s).
// Raw s_barrier + lgkmcnt(0) keeps stores in flight across barriers; the
// compiler's counted vmcnt before stage_write then only needs stores(t-1),
// which have a full tile period to drain in background.
#define BLK_PER_B   128
#define ROWS_PER_BLK 512
#define TILE_ROWS    64
#define TILES        (ROWS_PER_BLK / TILE_ROWS)   // 8
#define AROWS        66                            // 64 + 2 halo rows
#define ACHUNKS      (AROWS * 8)                   // 528 x 16B chunks

// LDS-hazard-only barrier (HK pattern, learn_hip m194-m201): the asm
// "memory" clobber is the compiler-level fence; s_barrier is convergent.
// Correctness: intra-block sharing is LDS-only (Abuf/OutT), so lgkmcnt(0)
// is sufficient; global stores need no cross-wave ordering.
#define BAR() do { asm volatile("s_waitcnt lgkmcnt(0)" ::: "memory"); \
                   __builtin_amdgcn_s_barrier(); } while (0)

typedef __bf16 bfrag  __attribute__((ext_vector_type(8)));
typedef float  floatx4 __attribute__((ext_vector_type(4)));

// ------------- prep: s, d, and folded kernel kmod[b][k][f][c] (bf16) -------
// kmod[b][k][f][c] = ker[k][c][f] * s[b][c] * d[b][f]
__global__ __launch_bounds__(256) void prep_kernel(
    const float* __restrict__ ltnt, const float* __restrict__ ker,
    const float* __restrict__ Wd,   const float* __restrict__ bd,
    __bf16* __restrict__ kmod)
{
    int b = blockIdx.x, tid = threadIdx.x;
    __shared__ float red[4][64];
    __shared__ float s_sh[64];
    __shared__ float d_sh[64];
    int f = tid & 63, p = tid >> 6;

    // s = softplus(ltnt @ Wd + bd) + 1
    float sum = 0.f;
    #pragma unroll 8
    for (int j = p * 64; j < p * 64 + 64; ++j)
        sum += ltnt[b * DLAT + j] * Wd[j * FILT + f];
    red[p][f] = sum;
    __syncthreads();
    if (tid < 64) {
        float tot = red[0][tid] + red[1][tid] + red[2][tid] + red[3][tid] + bd[tid];
        float sp = (tot > 20.f) ? tot : log1pf(expf(tot));
        s_sh[tid] = sp + 1.f;
    }
    __syncthreads();

    // d[f] = rsqrt( sum_{k,c} (ker[k,c,f]*s[c])^2 + eps )   (f32, matches ref)
    float s2 = 0.f;
    for (int k = 0; k < 3; ++k)
        #pragma unroll
        for (int c = p * 16; c < p * 16 + 16; ++c) {
            float w = ker[k * 4096 + c * 64 + f];
            float sc = s_sh[c];
            s2 += w * w * sc * sc;
        }
    __syncthreads();
    red[p][f] = s2;
    __syncthreads();
    if (tid < 64) {
        float tot = red[0][tid] + red[1][tid] + red[2][tid] + red[3][tid];
        d_sh[tid] = rsqrtf(tot + 1e-8f);
    }
    __syncthreads();

    // folded kernel, bf16, layout [k][f][c] contiguous in c
    for (int o = tid; o < 3 * 64 * 64; o += 256) {
        int k = o >> 12, ff = (o >> 6) & 63, c = o & 63;
        kmod[b * 12288 + o] = (__bf16)(ker[k * 4096 + c * 64 + ff] * s_sh[c] * d_sh[ff]);
    }
}

// ---------------------------- conv --------------------------------
__device__ __forceinline__ float4 scale4(float4 v, float s) {
    v.x *= s; v.y *= s; v.z *= s; v.w *= s; return v;
}

__device__ __forceinline__ bfrag cvt8(float4 a, float4 b) {
    bfrag r;
    r[0] = (__bf16)a.x; r[1] = (__bf16)a.y; r[2] = (__bf16)a.z; r[3] = (__bf16)a.w;
    r[4] = (__bf16)b.x; r[5] = (__bf16)b.y; r[6] = (__bf16)b.z; r[7] = (__bf16)b.w;
    return r;
}

// issue global loads for one A tile (rows r0-1 .. r0+64) into registers.
// chunk id = i*256+tid: rho = id>>3 (LDS row), c = id&7 (8-channel group).
// OOB (halo beyond batch edge, or id>=ACHUNKS) -> load row 0, scale 0.
__device__ __forceinline__ void stage_load(float4 pre[3][2],
                                           const float* __restrict__ xb,
                                           int r0, int tid) {
    #pragma unroll
    for (int i = 0; i < 3; ++i) {
        int id  = i * 256 + tid;
        int rho = id >> 3, c = id & 7;
        int g   = r0 - 1 + rho;
        bool ok = (id < ACHUNKS) && ((unsigned)g < (unsigned)SEQ);
        const float* p = xb + (size_t)(ok ? g : 0) * CH + c * 8;
        float s = ok ? 1.f : 0.f;
        pre[i][0] = scale4(*(const float4*)p, s);
        pre[i][1] = scale4(*(const float4*)(p + 4), s);
    }
}

// convert staged registers to bf16 and write to swizzled LDS A tile.
// element index = (rho*64 + c*8) ^ ((rho&7)<<3)  -- 16B-chunk XOR swizzle so
// ds_read_b128 at row-stride 128B spreads across bank groups (2-way max).
__device__ __forceinline__ void stage_write(__bf16* __restrict__ A,
                                            float4 pre[3][2], int tid) {
    #pragma unroll
    for (int i = 0; i < 3; ++i) {
        int id = i * 256 + tid;
        if (id < ACHUNKS) {
            int rho = id >> 3, c = id & 7;
            int idx = (rho * 64 + c * 8) ^ ((rho & 7) << 3);
            *(bfrag*)(A + idx) = cvt8(pre[i][0], pre[i][1]);
        }
    }
}

__global__ __launch_bounds__(256, 4) void conv_kernel(
    const float* __restrict__ data, const __bf16* __restrict__ kmod,
    float* __restrict__ out)
{
    __shared__ __bf16 Abuf[2][AROWS * 64];   // 2 x 8448 B, XOR-swizzled bf16
    __shared__ float  OutT[64 * 64];         // 16 KiB output transpose tile

    int tid  = threadIdx.x;
    int b    = blockIdx.x >> 7;              // 128 blocks per batch
    int blk  = blockIdx.x & (BLK_PER_B - 1);
    int wave = tid >> 6, lane = tid & 63;
    int m = lane & 15, q = lane >> 4;

    // B fragments for this wave's filter stripe (nt == wave): 6 frags = 24 regs
    const __bf16* kb = kmod + b * 12288;
    bfrag Bf[3][2];
    #pragma unroll
    for (int k = 0; k < 3; ++k)
        #pragma unroll
        for (int h = 0; h < 2; ++h)
            Bf[k][h] = *(const bfrag*)(kb + (k * 64 + wave * 16 + m) * 64 + h * 32 + q * 8);

    const float* xb = data + (size_t)b * SEQ * CH;
    float*       ob = out  + (size_t)b * SEQ * FILT;
    int base = blk * ROWS_PER_BLK;

    float4 pre[3][2];                        // 24 regs staged prefetch
    stage_load(pre, xb, base, tid);

    #pragma unroll 1
    for (int t = 0; t < TILES; ++t) {
        int r0 = base + t * TILE_ROWS;
        __bf16* A = Abuf[t & 1];

        stage_write(A, pre, tid);            // compiler waits vmcnt for loads only
        BAR();                                // S1: A ready; OutT(t-1) reads done

        if (t + 1 < TILES)                    // issue next tile's loads early;
            stage_load(pre, xb, r0 + TILE_ROWS, tid);   // drain under compute

        // ---- compute: 4 row-tiles x (3 taps x 2 ch-halves) MFMA ----
        floatx4 acc[4];
        #pragma unroll
        for (int rt = 0; rt < 4; ++rt) acc[rt] = floatx4{0, 0, 0, 0};

        #pragma unroll
        for (int rt = 0; rt < 4; ++rt) {
            #pragma unroll
            for (int k = 0; k < 3; ++k)
                #pragma unroll
                for (int h = 0; h < 2; ++h) {
                    int rho = rt * 16 + m + k;               // LDS row (r0-1 .. r0+64)
                    bfrag a = *(const bfrag*)(A +
                        ((rho * 64 + h * 32 + q * 8) ^ ((rho & 7) << 3)));
                    acc[rt] = __builtin_amdgcn_mfma_f32_16x16x32_bf16(
                        a, Bf[k][h], acc[rt], 0, 0, 0);
                }
        }

        // ---- acc -> OutT (swizzled: col ^ (q<<4) breaks q-lane 4-way) ----
        // acc[rt][r] = out[row = rt*16 + q*4 + r][col = wave*16 + m]
        #pragma unroll
        for (int rt = 0; rt < 4; ++rt)
            #pragma unroll
            for (int r = 0; r < 4; ++r) {
                int row = rt * 16 + q * 4 + r;
                int col = (wave * 16 + m) ^ (q << 4);
                OutT[row * 64 + col] = acc[rt][r];
            }
        BAR();                                // S2: OutT complete

        // ---- read full rows and store coalesced dwordx4 ----
        // id = it*256+tid: row = id>>4, c = id&15; stored col x lives at
        // x ^ ((row>>2 & 3)<<4); (row>>2) is uniform per instruction.
        #pragma unroll
        for (int it = 0; it < 4; ++it) {
            int id  = it * 256 + tid;
            int row = id >> 4, c = id & 15;
            int scol = (c * 4) ^ (((row >> 2) & 3) << 4);
            floatx4 v = *(const floatx4*)(OutT + row * 64 + scol);
            *(floatx4*)(ob + (size_t)(r0 + row) * FILT + c * 4) = v;
        }
        // stores stay outstanding across the next BAR(); they only must
        // commit before the counted vmcnt of stage_write two phases later.
    }
}

// ---------------------------------------------------------------------------
extern "C" void kernel_launch(void* const* d_in, const int* in_sizes, int n_in,
                              void* d_out, int out_size, void* d_ws, size_t ws_size,
                              hipStream_t stream) {
    const float* data = (const float*)d_in[0];
    const float* ltnt = (const float*)d_in[1];
    const float* ker  = (const float*)d_in[2];
    const float* Wd   = (const float*)d_in[3];
    const float* bd   = (const float*)d_in[4];
    float* out = (float*)d_out;

    __bf16* kmod = (__bf16*)d_ws;     // 8 * 12288 bf16 = 192 KiB

    prep_kernel<<<BATCH, 256, 0, stream>>>(ltnt, ker, Wd, bd, kmod);
    conv_kernel<<<BATCH * BLK_PER_B, 256, 0, stream>>>(data, kmod, out);
}

// Round 7
// 262.243 us; speedup vs baseline: 1.4517x; 1.0052x over previous
//
#include <hip/hip_runtime.h>

#define BATCH 8
#define SEQ   65536
#define CH    64
#define FILT  64
#define DLAT  256

// R7: LDS-pipe debottleneck. R4-R6 invariant (85us regardless of stores/
// barriers/occupancy) traced to LDS issue cycles: 4 waves re-reading the
// full A tile x3 taps + scalar OutT transpose = ~7.3K cy LDS per 6.4K cy
// tile period (pipe >100%). Fix:
//  (1) 2x2 wave split (32 rows x 32 filters each): A-read traffic halved,
//      Bf 24->48 VGPR (still fits 4 waves/SIMD).
//  (2) swapped MFMA operands mfma(Bf, Af, acc) -> C[filter][xrow]: lane
//      holds 4 CONSECUTIVE filters of one row -> acc stores directly to
//      global as dwordx4. OutT LDS transpose + second barrier DELETED.
// New LDS budget ~2.7K cy per period == at/below HBM roofline period.
#define BLK_PER_B   128
#define ROWS_PER_BLK 512
#define TILE_ROWS    64
#define TILES        (ROWS_PER_BLK / TILE_ROWS)   // 8
#define AROWS        66                            // 64 + 2 halo rows
#define ACHUNKS      (AROWS * 8)                   // 528 x 16B chunks

// LDS-hazard-only barrier: ds ops drained (lgkmcnt), global stores stay
// in flight. Intra-block sharing is LDS-only (Abuf), so this is sufficient.
#define BAR() do { asm volatile("s_waitcnt lgkmcnt(0)" ::: "memory"); \
                   __builtin_amdgcn_s_barrier(); } while (0)

typedef __bf16 bfrag  __attribute__((ext_vector_type(8)));
typedef float  floatx4 __attribute__((ext_vector_type(4)));

// ------------- prep: s, d, and folded kernel kmod[b][k][f][c] (bf16) -------
// kmod[b][k][f][c] = ker[k][c][f] * s[b][c] * d[b][f]
__global__ __launch_bounds__(256) void prep_kernel(
    const float* __restrict__ ltnt, const float* __restrict__ ker,
    const float* __restrict__ Wd,   const float* __restrict__ bd,
    __bf16* __restrict__ kmod)
{
    int b = blockIdx.x, tid = threadIdx.x;
    __shared__ float red[4][64];
    __shared__ float s_sh[64];
    __shared__ float d_sh[64];
    int f = tid & 63, p = tid >> 6;

    // s = softplus(ltnt @ Wd + bd) + 1
    float sum = 0.f;
    #pragma unroll 8
    for (int j = p * 64; j < p * 64 + 64; ++j)
        sum += ltnt[b * DLAT + j] * Wd[j * FILT + f];
    red[p][f] = sum;
    __syncthreads();
    if (tid < 64) {
        float tot = red[0][tid] + red[1][tid] + red[2][tid] + red[3][tid] + bd[tid];
        float sp = (tot > 20.f) ? tot : log1pf(expf(tot));
        s_sh[tid] = sp + 1.f;
    }
    __syncthreads();

    // d[f] = rsqrt( sum_{k,c} (ker[k,c,f]*s[c])^2 + eps )   (f32, matches ref)
    float s2 = 0.f;
    for (int k = 0; k < 3; ++k)
        #pragma unroll
        for (int c = p * 16; c < p * 16 + 16; ++c) {
            float w = ker[k * 4096 + c * 64 + f];
            float sc = s_sh[c];
            s2 += w * w * sc * sc;
        }
    __syncthreads();
    red[p][f] = s2;
    __syncthreads();
    if (tid < 64) {
        float tot = red[0][tid] + red[1][tid] + red[2][tid] + red[3][tid];
        d_sh[tid] = rsqrtf(tot + 1e-8f);
    }
    __syncthreads();

    // folded kernel, bf16, layout [k][f][c] contiguous in c
    for (int o = tid; o < 3 * 64 * 64; o += 256) {
        int k = o >> 12, ff = (o >> 6) & 63, c = o & 63;
        kmod[b * 12288 + o] = (__bf16)(ker[k * 4096 + c * 64 + ff] * s_sh[c] * d_sh[ff]);
    }
}

// ---------------------------- conv --------------------------------
__device__ __forceinline__ float4 scale4(float4 v, float s) {
    v.x *= s; v.y *= s; v.z *= s; v.w *= s; return v;
}

__device__ __forceinline__ bfrag cvt8(float4 a, float4 b) {
    bfrag r;
    r[0] = (__bf16)a.x; r[1] = (__bf16)a.y; r[2] = (__bf16)a.z; r[3] = (__bf16)a.w;
    r[4] = (__bf16)b.x; r[5] = (__bf16)b.y; r[6] = (__bf16)b.z; r[7] = (__bf16)b.w;
    return r;
}

// issue global loads for one A tile (rows r0-1 .. r0+64) into registers.
// chunk id = i*256+tid: rho = id>>3 (LDS row), c = id&7 (8-channel group).
// OOB (halo beyond batch edge, or id>=ACHUNKS) -> load row 0, scale 0.
__device__ __forceinline__ void stage_load(float4 pre[3][2],
                                           const float* __restrict__ xb,
                                           int r0, int tid) {
    #pragma unroll
    for (int i = 0; i < 3; ++i) {
        int id  = i * 256 + tid;
        int rho = id >> 3, c = id & 7;
        int g   = r0 - 1 + rho;
        bool ok = (id < ACHUNKS) && ((unsigned)g < (unsigned)SEQ);
        const float* p = xb + (size_t)(ok ? g : 0) * CH + c * 8;
        float s = ok ? 1.f : 0.f;
        pre[i][0] = scale4(*(const float4*)p, s);
        pre[i][1] = scale4(*(const float4*)(p + 4), s);
    }
}

// convert staged registers to bf16 and write to swizzled LDS A tile.
// element index = (rho*64 + c*8) ^ ((rho&7)<<3)  -- 16B-chunk XOR swizzle so
// ds_read_b128 at row-stride 128B spreads across bank groups (2-way max).
__device__ __forceinline__ void stage_write(__bf16* __restrict__ A,
                                            float4 pre[3][2], int tid) {
    #pragma unroll
    for (int i = 0; i < 3; ++i) {
        int id = i * 256 + tid;
        if (id < ACHUNKS) {
            int rho = id >> 3, c = id & 7;
            int idx = (rho * 64 + c * 8) ^ ((rho & 7) << 3);
            *(bfrag*)(A + idx) = cvt8(pre[i][0], pre[i][1]);
        }
    }
}

__global__ __launch_bounds__(256, 4) void conv_kernel(
    const float* __restrict__ data, const __bf16* __restrict__ kmod,
    float* __restrict__ out)
{
    __shared__ __bf16 Abuf[2][AROWS * 64];   // 2 x 8448 B, XOR-swizzled bf16

    int tid  = threadIdx.x;
    int b    = blockIdx.x >> 7;              // 128 blocks per batch
    int blk  = blockIdx.x & (BLK_PER_B - 1);
    int wave = tid >> 6, lane = tid & 63;
    int m = lane & 15, q = lane >> 4;
    int wr = wave >> 1, wf = wave & 1;       // row-half (32 rows), filter-half (32 f)

    // B fragments, M-side operand layout: lane(m,q) = filter (wf*32+nt*16+m),
    // channels q*8.. ; 12 frags = 48 VGPRs.
    const __bf16* kb = kmod + b * 12288;
    bfrag Bf[2][3][2];
    #pragma unroll
    for (int nt = 0; nt < 2; ++nt)
        #pragma unroll
        for (int k = 0; k < 3; ++k)
            #pragma unroll
            for (int h = 0; h < 2; ++h)
                Bf[nt][k][h] = *(const bfrag*)(kb +
                    (k * 64 + wf * 32 + nt * 16 + m) * 64 + h * 32 + q * 8);

    const float* xb = data + (size_t)b * SEQ * CH;
    float*       ob = out  + (size_t)b * SEQ * FILT;
    int base = blk * ROWS_PER_BLK;

    float4 pre[3][2];                        // 24 regs staged prefetch
    stage_load(pre, xb, base, tid);

    #pragma unroll 1
    for (int t = 0; t < TILES; ++t) {
        int r0 = base + t * TILE_ROWS;
        __bf16* A = Abuf[t & 1];

        stage_write(A, pre, tid);            // counted vmcnt: loads(t) only
        BAR();                                // A(t) ready; A(t-1) reads done

        if (t + 1 < TILES)                    // issue next tile's loads early
            stage_load(pre, xb, r0 + TILE_ROWS, tid);

        // ---- compute: 2 row-tiles x 2 filter-tiles, swapped operands ----
        // acc[rt][nt] = C[filter][xrow]: lane(m,q) reg r ->
        //   out[row = r0 + wr*32 + rt*16 + m][filt = wf*32 + nt*16 + q*4 + r]
        floatx4 acc[2][2];
        #pragma unroll
        for (int rt = 0; rt < 2; ++rt)
            #pragma unroll
            for (int nt = 0; nt < 2; ++nt)
                acc[rt][nt] = floatx4{0, 0, 0, 0};

        #pragma unroll
        for (int rt = 0; rt < 2; ++rt) {
            #pragma unroll
            for (int k = 0; k < 3; ++k)
                #pragma unroll
                for (int h = 0; h < 2; ++h) {
                    int rho = wr * 32 + rt * 16 + m + k;     // LDS row (r0-1 ..)
                    bfrag a = *(const bfrag*)(A +
                        ((rho * 64 + h * 32 + q * 8) ^ ((rho & 7) << 3)));
                    #pragma unroll
                    for (int nt = 0; nt < 2; ++nt)
                        acc[rt][nt] = __builtin_amdgcn_mfma_f32_16x16x32_bf16(
                            Bf[nt][k][h], a, acc[rt][nt], 0, 0, 0);
                }
        }

        // ---- direct global stores: dwordx4 = 4 consecutive filters ----
        // per instr: 16 rows x 64B contiguous segments -- L2 write-combines.
        #pragma unroll
        for (int rt = 0; rt < 2; ++rt) {
            int row = r0 + wr * 32 + rt * 16 + m;
            #pragma unroll
            for (int nt = 0; nt < 2; ++nt)
                *(floatx4*)(ob + (size_t)row * FILT + wf * 32 + nt * 16 + q * 4)
                    = acc[rt][nt];
        }
        // stores stay outstanding across BAR(); they drain in background and
        // are only implicitly bounded by the counted vmcnt of stage_write.
    }
}

// ---------------------------------------------------------------------------
extern "C" void kernel_launch(void* const* d_in, const int* in_sizes, int n_in,
                              void* d_out, int out_size, void* d_ws, size_t ws_size,
                              hipStream_t stream) {
    const float* data = (const float*)d_in[0];
    const float* ltnt = (const float*)d_in[1];
    const float* ker  = (const float*)d_in[2];
    const float* Wd   = (const float*)d_in[3];
    const float* bd   = (const float*)d_in[4];
    float* out = (float*)d_out;

    __bf16* kmod = (__bf16*)d_ws;     // 8 * 12288 bf16 = 192 KiB

    prep_kernel<<<BATCH, 256, 0, stream>>>(ltnt, ker, Wd, bd, kmod);
    conv_kernel<<<BATCH * BLK_PER_B, 256, 0, stream>>>(data, kmod, out);
}